// Round 1
// baseline (7457.407 us; speedup 1.0000x reference)
//
#include <hip/hip_runtime.h>
#include <math.h>

#define Bq 4
#define Hq 16
#define Nq 4096
#define Dq 64
#define Mq 128
#define EPS_PHI 1e-4f
#define EPS_DEN 1e-6f
#define SCALE 0.35355339059327373f   /* 64^-0.25 = 2^-1.5 */
#define INVSQRT_M 0.08838834764831845f /* 1/sqrt(128) = 2^-3.5 */

// ---------------------------------------------------------------------------
// Kernel 1: rowQ[row] = 0.5 * || scale*q_row ||^2   (one wave per row)
// ---------------------------------------------------------------------------
__global__ void qsumsq_kernel(const float* __restrict__ q, float* __restrict__ rowQ) {
    const int lane = threadIdx.x & 63;
    const int wid  = (blockIdx.x * blockDim.x + threadIdx.x) >> 6;
    const int nw   = (gridDim.x * blockDim.x) >> 6;
    const int totalRows = Bq * Hq * Nq;
    for (int row = wid; row < totalRows; row += nw) {
        float x = q[(size_t)row * 64 + lane] * SCALE;
        float s = x * x;
        #pragma unroll
        for (int o = 1; o <= 32; o <<= 1) s += __shfl_xor(s, o);
        if (lane == 0) rowQ[row] = 0.5f * s;
    }
}

// ---------------------------------------------------------------------------
// Kernel 2: per-block max of log_phi_k over 8 rows x 128 m; also rowK sumsq
// ---------------------------------------------------------------------------
__global__ void kstat_kernel(const float* __restrict__ kin, const float* __restrict__ omega,
                             float* __restrict__ rowK, float* __restrict__ partial) {
    const int t = threadIdx.x;
    const int base = blockIdx.x * 8;
    __shared__ __align__(16) float kr[8][64];
    __shared__ float hrow[8];
    __shared__ float wred[4];

    #pragma unroll
    for (int i = 0; i < 2; ++i) {
        int li = t + i * 256;
        int r = li >> 6, d = li & 63;
        kr[r][d] = kin[(size_t)(base + r) * 64 + d] * SCALE;
    }
    __syncthreads();
    if (t < 8) {
        float s = 0.f;
        for (int d = 0; d < 64; ++d) { float x = kr[t][d]; s += x * x; }
        s *= 0.5f;
        hrow[t] = s;
        rowK[base + t] = s;
    }
    // omega row for m = t & 127 into registers
    const int m = t & 127;
    float om[64];
    {
        const float4* o4 = (const float4*)(omega + (size_t)m * 64);
        #pragma unroll
        for (int j = 0; j < 16; ++j) {
            float4 w = o4[j];
            om[4*j] = w.x; om[4*j+1] = w.y; om[4*j+2] = w.z; om[4*j+3] = w.w;
        }
    }
    __syncthreads();
    const int rp = t >> 7;
    float bmax = -1e30f;
    for (int j = 0; j < 4; ++j) {
        int r = rp + 2 * j;
        const float4* x4 = (const float4*)kr[r];
        float d0 = 0, d1 = 0, d2 = 0, d3 = 0;
        #pragma unroll
        for (int jj = 0; jj < 16; ++jj) {
            float4 w = x4[jj];
            d0 += om[4*jj]   * w.x;
            d1 += om[4*jj+1] * w.y;
            d2 += om[4*jj+2] * w.z;
            d3 += om[4*jj+3] * w.w;
        }
        float dot = (d0 + d1) + (d2 + d3);
        bmax = fmaxf(bmax, dot - hrow[r]);
    }
    #pragma unroll
    for (int o = 1; o <= 32; o <<= 1) bmax = fmaxf(bmax, __shfl_xor(bmax, o));
    if ((t & 63) == 0) wred[t >> 6] = bmax;
    __syncthreads();
    if (t == 0)
        partial[blockIdx.x] = fmaxf(fmaxf(wred[0], wred[1]), fmaxf(wred[2], wred[3]));
}

// ---------------------------------------------------------------------------
// Kernel 3: reduce partial maxes -> gmax scalar
// ---------------------------------------------------------------------------
__global__ void gmax_kernel(const float* __restrict__ partial, int n, float* __restrict__ gmax) {
    float m = -1e30f;
    for (int i = threadIdx.x; i < n; i += 256) m = fmaxf(m, partial[i]);
    #pragma unroll
    for (int o = 1; o <= 32; o <<= 1) m = fmaxf(m, __shfl_xor(m, o));
    __shared__ float w[4];
    if ((threadIdx.x & 63) == 0) w[threadIdx.x >> 6] = m;
    __syncthreads();
    if (threadIdx.x == 0) gmax[0] = fmaxf(fmaxf(w[0], w[1]), fmaxf(w[2], w[3]));
}

// ---------------------------------------------------------------------------
// Kernel 4: causal linear-attention scan. One block per (b,h), 256 threads.
// S[128][64] held in registers: thread t owns d = t&63, m in [(t>>6)*32, +32).
// ---------------------------------------------------------------------------
__global__ __launch_bounds__(256) void scan_kernel(
    const float* __restrict__ q, const float* __restrict__ kin, const float* __restrict__ vin,
    const float* __restrict__ omega, const float* __restrict__ rowQ, const float* __restrict__ rowK,
    const float* __restrict__ gmaxp, float* __restrict__ out) {
    const int t    = threadIdx.x;
    const int bh   = blockIdx.x;
    const int lane = t & 63;
    const int wid  = t >> 6;
    const size_t rowbase = (size_t)bh * Nq;

    __shared__ __align__(16) float xq[64];
    __shared__ __align__(16) float xk[64];
    __shared__ __align__(16) float xv[64];
    __shared__ __align__(16) float pq_s[128];
    __shared__ __align__(16) float pk_s[128];
    __shared__ float red[256];
    __shared__ float wmax[2], wden[2];
    __shared__ float den_s;

    const int m = t & 127;
    float om[64];
    {
        const float4* o4 = (const float4*)(omega + (size_t)m * 64);
        #pragma unroll
        for (int j = 0; j < 16; ++j) {
            float4 w = o4[j];
            om[4*j] = w.x; om[4*j+1] = w.y; om[4*j+2] = w.z; om[4*j+3] = w.w;
        }
    }
    const float gmax = gmaxp[0];
    float S[32];
    #pragma unroll
    for (int i = 0; i < 32; ++i) S[i] = 0.f;
    float z = 0.f;
    const int d_own = t & 63;
    const int mbase = (t >> 6) * 32;

    const float* qb = q   + rowbase * 64;
    const float* kb = kin + rowbase * 64;
    const float* vb = vin + rowbase * 64;

    float pref = 0.f;
    if      (t < 64)  pref = qb[t];
    else if (t < 128) pref = kb[t - 64];
    else if (t < 192) pref = vb[t - 128];

    for (int n = 0; n < Nq; ++n) {
        if      (t < 64)  xq[t]       = pref * SCALE;
        else if (t < 128) xk[t - 64]  = pref * SCALE;
        else if (t < 192) xv[t - 128] = pref;
        __syncthreads();                                   // B1: rows staged

        if (n + 1 < Nq) {                                  // prefetch next row
            size_t off = (size_t)(n + 1) * 64;
            if      (t < 64)  pref = qb[off + t];
            else if (t < 128) pref = kb[off + t - 64];
            else if (t < 192) pref = vb[off + t - 128];
        }

        float h = (t < 128) ? rowQ[rowbase + n] : rowK[rowbase + n];

        // phase A: dot(omega_m, x_row); x reads are wave-uniform (broadcast)
        const float* x = (t < 128) ? xq : xk;
        const float4* x4 = (const float4*)x;
        float d0 = 0, d1 = 0, d2 = 0, d3 = 0;
        #pragma unroll
        for (int j = 0; j < 16; ++j) {
            float4 w = x4[j];
            d0 += om[4*j]   * w.x;
            d1 += om[4*j+1] * w.y;
            d2 += om[4*j+2] * w.z;
            d3 += om[4*j+3] * w.w;
        }
        float lg = ((d0 + d1) + (d2 + d3)) - h;

        if (t < 128) {
            float mx = lg;
            #pragma unroll
            for (int o = 1; o <= 32; o <<= 1) mx = fmaxf(mx, __shfl_xor(mx, o));
            if (lane == 0) wmax[wid] = mx;
        } else {
            pk_s[m] = expf(lg - gmax) * INVSQRT_M + EPS_PHI;
        }
        __syncthreads();                                   // B2: wmax + pk ready

        if (t < 128) {
            float rmax = fmaxf(wmax[0], wmax[1]);
            float pq = expf(lg - rmax) * INVSQRT_M + EPS_PHI;
            pq_s[m] = pq;
            z += pk_s[m];
            float dp = pq * z;
            #pragma unroll
            for (int o = 1; o <= 32; o <<= 1) dp += __shfl_xor(dp, o);
            if (lane == 0) wden[wid] = dp;
        }
        __syncthreads();                                   // B3: pq + den parts

        // phase B: S += pk (x) v ; num partial = sum_m pq[m]*S[m][d]
        float vd = xv[d_own];
        const float4* pk4 = (const float4*)(pk_s + mbase);
        const float4* pq4 = (const float4*)(pq_s + mbase);
        float n0 = 0, n1 = 0, n2 = 0, n3 = 0;
        #pragma unroll
        for (int j = 0; j < 8; ++j) {
            float4 a = pk4[j];
            float4 b = pq4[j];
            S[4*j]   += a.x * vd;  n0 += b.x * S[4*j];
            S[4*j+1] += a.y * vd;  n1 += b.y * S[4*j+1];
            S[4*j+2] += a.z * vd;  n2 += b.z * S[4*j+2];
            S[4*j+3] += a.w * vd;  n3 += b.w * S[4*j+3];
        }
        red[t] = (n0 + n1) + (n2 + n3);
        if (t == 0) den_s = wden[0] + wden[1] + EPS_DEN;
        __syncthreads();                                   // B4: partials ready

        if (t < 64) {
            float num = red[t] + red[t + 64] + red[t + 128] + red[t + 192];
            out[(rowbase + n) * 64 + t] = num / den_s;
        }
        // no trailing barrier needed: next-iter LDS writes don't alias live reads
    }
}

// ---------------------------------------------------------------------------
extern "C" void kernel_launch(void* const* d_in, const int* in_sizes, int n_in,
                              void* d_out, int out_size, void* d_ws, size_t ws_size,
                              hipStream_t stream) {
    const float* q     = (const float*)d_in[0];
    const float* k     = (const float*)d_in[1];
    const float* v     = (const float*)d_in[2];
    const float* omega = (const float*)d_in[3];
    float* out = (float*)d_out;
    float* ws  = (float*)d_ws;

    const int totalRows = Bq * Hq * Nq;        // 262144
    float* rowQ    = ws;                       // 262144 floats
    float* rowK    = rowQ + totalRows;         // 262144 floats
    float* partial = rowK + totalRows;         // 32768 floats
    float* gmax    = partial + totalRows / 8;  // 1 float

    qsumsq_kernel<<<1024, 256, 0, stream>>>(q, rowQ);
    kstat_kernel<<<totalRows / 8, 256, 0, stream>>>(k, omega, rowK, partial);
    gmax_kernel<<<1, 256, 0, stream>>>(partial, totalRows / 8, gmax);
    scan_kernel<<<Bq * Hq, 256, 0, stream>>>(q, k, v, omega, rowQ, rowK, gmax, out);
}

// Round 2
// 1525.495 us; speedup vs baseline: 4.8885x; 4.8885x over previous
//
#include <hip/hip_runtime.h>
#include <math.h>

#define Bq 4
#define Hq 16
#define Nq 4096
#define Dq 64
#define Mq 128
#define EPS_PHI 1e-4f
#define EPS_DEN 1e-6f
#define SCALE 0.35355339059327373f     /* 64^-0.25 */
#define INVSQRT_M 0.08838834764831845f /* 1/sqrt(128) */
#define STATE_STRIDE 8320              /* 128*64 S + 128 z */

// ---------------------------------------------------------------------------
// Kernel 1: rowQ[row] = 0.5 * || scale*q_row ||^2   (one wave per row)
// ---------------------------------------------------------------------------
__global__ void qsumsq_kernel(const float* __restrict__ q, float* __restrict__ rowQ) {
    const int lane = threadIdx.x & 63;
    const int wid  = (blockIdx.x * blockDim.x + threadIdx.x) >> 6;
    const int nw   = (gridDim.x * blockDim.x) >> 6;
    const int totalRows = Bq * Hq * Nq;
    for (int row = wid; row < totalRows; row += nw) {
        float x = q[(size_t)row * 64 + lane] * SCALE;
        float s = x * x;
        #pragma unroll
        for (int o = 1; o <= 32; o <<= 1) s += __shfl_xor(s, o);
        if (lane == 0) rowQ[row] = 0.5f * s;
    }
}

// ---------------------------------------------------------------------------
// Kernel 2: per-block max of log_phi_k over 8 rows x 128 m; also rowK sumsq
// ---------------------------------------------------------------------------
__global__ void kstat_kernel(const float* __restrict__ kin, const float* __restrict__ omega,
                             float* __restrict__ rowK, float* __restrict__ partial) {
    const int t = threadIdx.x;
    const int base = blockIdx.x * 8;
    __shared__ __align__(16) float kr[8][64];
    __shared__ float hrow[8];
    __shared__ float wred[4];

    #pragma unroll
    for (int i = 0; i < 2; ++i) {
        int li = t + i * 256;
        int r = li >> 6, d = li & 63;
        kr[r][d] = kin[(size_t)(base + r) * 64 + d] * SCALE;
    }
    __syncthreads();
    if (t < 8) {
        float s = 0.f;
        for (int d = 0; d < 64; ++d) { float x = kr[t][d]; s += x * x; }
        s *= 0.5f;
        hrow[t] = s;
        rowK[base + t] = s;
    }
    const int m = t & 127;
    float om[64];
    {
        const float4* o4 = (const float4*)(omega + (size_t)m * 64);
        #pragma unroll
        for (int j = 0; j < 16; ++j) {
            float4 w = o4[j];
            om[4*j] = w.x; om[4*j+1] = w.y; om[4*j+2] = w.z; om[4*j+3] = w.w;
        }
    }
    __syncthreads();
    const int rp = t >> 7;
    float bmax = -1e30f;
    for (int j = 0; j < 4; ++j) {
        int r = rp + 2 * j;
        const float4* x4 = (const float4*)kr[r];
        float d0 = 0, d1 = 0, d2 = 0, d3 = 0;
        #pragma unroll
        for (int jj = 0; jj < 16; ++jj) {
            float4 w = x4[jj];
            d0 += om[4*jj]   * w.x;
            d1 += om[4*jj+1] * w.y;
            d2 += om[4*jj+2] * w.z;
            d3 += om[4*jj+3] * w.w;
        }
        float dot = (d0 + d1) + (d2 + d3);
        bmax = fmaxf(bmax, dot - hrow[r]);
    }
    #pragma unroll
    for (int o = 1; o <= 32; o <<= 1) bmax = fmaxf(bmax, __shfl_xor(bmax, o));
    if ((t & 63) == 0) wred[t >> 6] = bmax;
    __syncthreads();
    if (t == 0)
        partial[blockIdx.x] = fmaxf(fmaxf(wred[0], wred[1]), fmaxf(wred[2], wred[3]));
}

// ---------------------------------------------------------------------------
// Kernel 3: reduce partial maxes -> gmax scalar
// ---------------------------------------------------------------------------
__global__ void gmax_kernel(const float* __restrict__ partial, int n, float* __restrict__ gmax) {
    float m = -1e30f;
    for (int i = threadIdx.x; i < n; i += 256) m = fmaxf(m, partial[i]);
    #pragma unroll
    for (int o = 1; o <= 32; o <<= 1) m = fmaxf(m, __shfl_xor(m, o));
    __shared__ float w[4];
    if ((threadIdx.x & 63) == 0) w[threadIdx.x >> 6] = m;
    __syncthreads();
    if (threadIdx.x == 0) gmax[0] = fmaxf(fmaxf(w[0], w[1]), fmaxf(w[2], w[3]));
}

// ---------------------------------------------------------------------------
// Kernel 4: per-chunk state deltas. One block per (b,h,chunk), 256 threads.
// ΔS[128][64] in regs (thread owns d=t&63, m in [(t>>6)*32,+32)), Δz[128].
// ---------------------------------------------------------------------------
__global__ __launch_bounds__(256) void chunkstate_kernel(
    const float* __restrict__ kin, const float* __restrict__ vin,
    const float* __restrict__ omega, const float* __restrict__ rowK,
    const float* __restrict__ gmaxp, float* __restrict__ Sbuf, int C, int L) {
    const int t  = threadIdx.x;
    const int bx = blockIdx.x;
    const int bh = bx / C, c = bx - bh * C;
    const size_t rowbase = (size_t)bh * Nq + (size_t)c * L;
    const float* kb = kin + rowbase * 64;
    const float* vb = vin + rowbase * 64;

    __shared__ __align__(16) float xk[4][64];
    __shared__ __align__(16) float xv[4][64];
    __shared__ __align__(16) float pk_s[4][128];

    const int m = t & 127;
    const int p = t >> 7;
    float om[64];
    {
        const float4* o4 = (const float4*)(omega + (size_t)m * 64);
        #pragma unroll
        for (int j = 0; j < 16; ++j) {
            float4 w = o4[j];
            om[4*j] = w.x; om[4*j+1] = w.y; om[4*j+2] = w.z; om[4*j+3] = w.w;
        }
    }
    const float gmax = gmaxp[0];
    float S[32];
    #pragma unroll
    for (int i = 0; i < 32; ++i) S[i] = 0.f;
    float z = 0.f;
    const int d_own = t & 63;
    const int mbase = (t >> 6) * 32;
    const int r0 = t >> 6, dd = t & 63;

    float pk_ = kb[t];
    float pv_ = vb[t];

    for (int g = 0; g < L; g += 4) {
        xk[r0][dd] = pk_ * SCALE;
        xv[r0][dd] = pv_;
        __syncthreads();                                  // B1
        if (g + 4 < L) {
            pk_ = kb[(size_t)(g + 4) * 64 + t];
            pv_ = vb[(size_t)(g + 4) * 64 + t];
        }
        float h0 = rowK[rowbase + g + p];
        float h2 = rowK[rowbase + g + p + 2];
        {
            const float4* x4 = (const float4*)xk[p];
            float d0 = 0, d1 = 0, d2 = 0, d3 = 0;
            #pragma unroll
            for (int jj = 0; jj < 16; ++jj) {
                float4 w = x4[jj];
                d0 += om[4*jj]   * w.x; d1 += om[4*jj+1] * w.y;
                d2 += om[4*jj+2] * w.z; d3 += om[4*jj+3] * w.w;
            }
            float lg = ((d0 + d1) + (d2 + d3)) - h0;
            pk_s[p][m] = expf(lg - gmax) * INVSQRT_M + EPS_PHI;
        }
        {
            const float4* x4 = (const float4*)xk[p + 2];
            float d0 = 0, d1 = 0, d2 = 0, d3 = 0;
            #pragma unroll
            for (int jj = 0; jj < 16; ++jj) {
                float4 w = x4[jj];
                d0 += om[4*jj]   * w.x; d1 += om[4*jj+1] * w.y;
                d2 += om[4*jj+2] * w.z; d3 += om[4*jj+3] * w.w;
            }
            float lg = ((d0 + d1) + (d2 + d3)) - h2;
            pk_s[p + 2][m] = expf(lg - gmax) * INVSQRT_M + EPS_PHI;
        }
        __syncthreads();                                  // B2
        #pragma unroll
        for (int r = 0; r < 4; ++r) {
            float vd = xv[r][d_own];
            const float4* a4 = (const float4*)(pk_s[r] + mbase);
            #pragma unroll
            for (int j = 0; j < 8; ++j) {
                float4 a = a4[j];
                S[4*j]   += a.x * vd;
                S[4*j+1] += a.y * vd;
                S[4*j+2] += a.z * vd;
                S[4*j+3] += a.w * vd;
            }
        }
        if (t < 128) z += pk_s[0][m] + pk_s[1][m] + pk_s[2][m] + pk_s[3][m];
        __syncthreads();                                  // B3 (protect xk/xv/pk_s)
    }
    float* sb = Sbuf + (size_t)bx * STATE_STRIDE;
    #pragma unroll
    for (int j = 0; j < 32; ++j) sb[(mbase + j) * 64 + d_own] = S[j];
    if (t < 128) sb[8192 + m] = z;
}

// ---------------------------------------------------------------------------
// Kernel 5: in-place exclusive prefix of chunk states per (b,h). 64 blocks.
// ---------------------------------------------------------------------------
__global__ __launch_bounds__(256) void prefix_kernel(float* __restrict__ Sbuf, int C) {
    const int bh = blockIdx.x;
    const int t  = threadIdx.x;
    for (int e = t; e < STATE_STRIDE; e += 256) {
        float running = 0.f;
        for (int c = 0; c < C; ++c) {
            size_t idx = ((size_t)bh * C + c) * STATE_STRIDE + e;
            float tmp = Sbuf[idx];
            Sbuf[idx] = running;
            running += tmp;
        }
    }
}

// ---------------------------------------------------------------------------
// Kernel 6: replay. One block per (b,h,chunk); starts from exclusive prefix
// state; 4 rows per barrier group; recurrence carried in registers.
// ---------------------------------------------------------------------------
__global__ __launch_bounds__(256) void replay_kernel(
    const float* __restrict__ q, const float* __restrict__ kin, const float* __restrict__ vin,
    const float* __restrict__ omega, const float* __restrict__ rowQ, const float* __restrict__ rowK,
    const float* __restrict__ gmaxp, const float* __restrict__ Sbuf,
    float* __restrict__ out, int C, int L) {
    const int t  = threadIdx.x;
    const int bx = blockIdx.x;
    const int bh = bx / C, c = bx - bh * C;
    const size_t rowbase = (size_t)bh * Nq + (size_t)c * L;
    const float* qb = q   + rowbase * 64;
    const float* kb = kin + rowbase * 64;
    const float* vb = vin + rowbase * 64;
    float* outb = out + rowbase * 64;

    __shared__ __align__(16) float xq[4][64];
    __shared__ __align__(16) float xk[4][64];
    __shared__ __align__(16) float xv[4][64];
    __shared__ __align__(16) float qlg[4][128];
    __shared__ __align__(16) float pq_s[4][128];
    __shared__ __align__(16) float pk_s[4][128];
    __shared__ __align__(16) float red[4][256];
    __shared__ float wden[4][2];

    const int m = t & 127;
    const int p = t >> 7;
    const int lane = t & 63;
    const int w = t >> 6;          // wave id (also row id for out phase)
    const int d_own = t & 63;
    const int mbase = (t >> 6) * 32;

    float om[64];
    {
        const float4* o4 = (const float4*)(omega + (size_t)m * 64);
        #pragma unroll
        for (int j = 0; j < 16; ++j) {
            float4 wv = o4[j];
            om[4*j] = wv.x; om[4*j+1] = wv.y; om[4*j+2] = wv.z; om[4*j+3] = wv.w;
        }
    }
    const float gmax = gmaxp[0];

    const float* sb = Sbuf + (size_t)bx * STATE_STRIDE;
    float S[32];
    #pragma unroll
    for (int j = 0; j < 32; ++j) S[j] = sb[(mbase + j) * 64 + d_own];
    float z = (t < 128) ? sb[8192 + m] : 0.f;

    float pq_ = qb[t];
    float pk_ = kb[t];
    float pv_ = vb[t];

    for (int g = 0; g < L; g += 4) {
        xq[w][lane] = pq_ * SCALE;
        xk[w][lane] = pk_ * SCALE;
        xv[w][lane] = pv_;
        __syncthreads();                                  // B1
        if (g + 4 < L) {
            size_t off = (size_t)(g + 4) * 64 + t;
            pq_ = qb[off]; pk_ = kb[off]; pv_ = vb[off];
        }
        float hq0 = rowQ[rowbase + g + p];
        float hq2 = rowQ[rowbase + g + p + 2];
        float hk0 = rowK[rowbase + g + p];
        float hk2 = rowK[rowbase + g + p + 2];
        {
            const float4* x4 = (const float4*)xq[p];
            float d0 = 0, d1 = 0, d2 = 0, d3 = 0;
            #pragma unroll
            for (int jj = 0; jj < 16; ++jj) {
                float4 wv = x4[jj];
                d0 += om[4*jj]   * wv.x; d1 += om[4*jj+1] * wv.y;
                d2 += om[4*jj+2] * wv.z; d3 += om[4*jj+3] * wv.w;
            }
            qlg[p][m] = ((d0 + d1) + (d2 + d3)) - hq0;
        }
        {
            const float4* x4 = (const float4*)xq[p + 2];
            float d0 = 0, d1 = 0, d2 = 0, d3 = 0;
            #pragma unroll
            for (int jj = 0; jj < 16; ++jj) {
                float4 wv = x4[jj];
                d0 += om[4*jj]   * wv.x; d1 += om[4*jj+1] * wv.y;
                d2 += om[4*jj+2] * wv.z; d3 += om[4*jj+3] * wv.w;
            }
            qlg[p + 2][m] = ((d0 + d1) + (d2 + d3)) - hq2;
        }
        {
            const float4* x4 = (const float4*)xk[p];
            float d0 = 0, d1 = 0, d2 = 0, d3 = 0;
            #pragma unroll
            for (int jj = 0; jj < 16; ++jj) {
                float4 wv = x4[jj];
                d0 += om[4*jj]   * wv.x; d1 += om[4*jj+1] * wv.y;
                d2 += om[4*jj+2] * wv.z; d3 += om[4*jj+3] * wv.w;
            }
            float lg = ((d0 + d1) + (d2 + d3)) - hk0;
            pk_s[p][m] = expf(lg - gmax) * INVSQRT_M + EPS_PHI;
        }
        {
            const float4* x4 = (const float4*)xk[p + 2];
            float d0 = 0, d1 = 0, d2 = 0, d3 = 0;
            #pragma unroll
            for (int jj = 0; jj < 16; ++jj) {
                float4 wv = x4[jj];
                d0 += om[4*jj]   * wv.x; d1 += om[4*jj+1] * wv.y;
                d2 += om[4*jj+2] * wv.z; d3 += om[4*jj+3] * wv.w;
            }
            float lg = ((d0 + d1) + (d2 + d3)) - hk2;
            pk_s[p + 2][m] = expf(lg - gmax) * INVSQRT_M + EPS_PHI;
        }
        __syncthreads();                                  // B2
        {   // wave w handles q row w: rowmax + pq
            float a = qlg[w][lane];
            float b = qlg[w][lane + 64];
            float mx = fmaxf(a, b);
            #pragma unroll
            for (int o = 1; o <= 32; o <<= 1) mx = fmaxf(mx, __shfl_xor(mx, o));
            pq_s[w][lane]      = expf(a - mx) * INVSQRT_M + EPS_PHI;
            pq_s[w][lane + 64] = expf(b - mx) * INVSQRT_M + EPS_PHI;
        }
        __syncthreads();                                  // B3
        #pragma unroll
        for (int r = 0; r < 4; ++r) {
            if (t < 128) {
                z += pk_s[r][m];
                float dp = pq_s[r][m] * z;
                #pragma unroll
                for (int o = 1; o <= 32; o <<= 1) dp += __shfl_xor(dp, o);
                if (lane == 0) wden[r][p ? 1 : (t >> 6)] = dp;  // wave0->0, wave1->1
            }
            float vd = xv[r][d_own];
            const float4* a4 = (const float4*)(pk_s[r] + mbase);
            const float4* b4 = (const float4*)(pq_s[r] + mbase);
            float n0 = 0, n1 = 0, n2 = 0, n3 = 0;
            #pragma unroll
            for (int j = 0; j < 8; ++j) {
                float4 a = a4[j];
                float4 b = b4[j];
                S[4*j]   += a.x * vd;  n0 += b.x * S[4*j];
                S[4*j+1] += a.y * vd;  n1 += b.y * S[4*j+1];
                S[4*j+2] += a.z * vd;  n2 += b.z * S[4*j+2];
                S[4*j+3] += a.w * vd;  n3 += b.w * S[4*j+3];
            }
            red[r][t] = (n0 + n1) + (n2 + n3);
        }
        __syncthreads();                                  // B4
        {   // out: thread t -> row w, col d_own
            float num = red[w][d_own] + red[w][d_own + 64] +
                        red[w][d_own + 128] + red[w][d_own + 192];
            float den = wden[w][0] + wden[w][1] + EPS_DEN;
            outb[(size_t)(g + w) * 64 + d_own] = num / den;
        }
        // no trailing barrier: next-iter writes (xq/xk/xv now, red/wden after B3)
        // never alias the red/wden reads above without an intervening barrier
    }
}

// ---------------------------------------------------------------------------
extern "C" void kernel_launch(void* const* d_in, const int* in_sizes, int n_in,
                              void* d_out, int out_size, void* d_ws, size_t ws_size,
                              hipStream_t stream) {
    const float* q     = (const float*)d_in[0];
    const float* k     = (const float*)d_in[1];
    const float* v     = (const float*)d_in[2];
    const float* omega = (const float*)d_in[3];
    float* out = (float*)d_out;
    float* ws  = (float*)d_ws;

    const int totalRows = Bq * Hq * Nq;          // 262144
    float* rowQ    = ws;                         // 262144
    float* rowK    = rowQ + totalRows;           // 262144
    float* partial = rowK + totalRows;           // 32768
    float* gmax    = partial + totalRows / 8;    // 1 (+pad)
    float* Sbuf    = gmax + 16;

    const size_t base_floats = (size_t)totalRows * 2 + totalRows / 8 + 16;
    int C = 32;
    while (C > 1 && (base_floats + (size_t)64 * C * STATE_STRIDE) * 4 > ws_size) C >>= 1;
    const int L = Nq / C;

    qsumsq_kernel<<<1024, 256, 0, stream>>>(q, rowQ);
    kstat_kernel<<<totalRows / 8, 256, 0, stream>>>(k, omega, rowK, partial);
    gmax_kernel<<<1, 256, 0, stream>>>(partial, totalRows / 8, gmax);
    chunkstate_kernel<<<64 * C, 256, 0, stream>>>(k, v, omega, rowK, gmax, Sbuf, C, L);
    prefix_kernel<<<64, 256, 0, stream>>>(Sbuf, C);
    replay_kernel<<<64 * C, 256, 0, stream>>>(q, k, v, omega, rowQ, rowK, gmax, Sbuf, out, C, L);
}

// Round 3
// 556.678 us; speedup vs baseline: 13.3963x; 2.7404x over previous
//
#include <hip/hip_runtime.h>
#include <math.h>

#define Bq 4
#define Hq 16
#define Nq 4096
#define Dq 64
#define Mq 128
#define Cq 32                          /* chunks per (b,h); L = 128 */
#define Lq 128
#define EPS_PHI 1e-4f
#define EPS_DEN 1e-6f
#define SCALE 0.35355339059327373f     /* 64^-0.25 */
#define INVSQRT_M 0.08838834764831845f /* 1/sqrt(128) */
#define STATE_STRIDE 8320              /* 128*64 S + 128 z */

#define PSTR 264   /* [A_s | PQ] row stride, bf16 (256+8: 16B-mult, bank-rotating) */
#define KSTR 136   /* PK / PKt / Vt row stride, bf16 (128+8) */
#define WSTR 264   /* Wt row stride, bf16 */

typedef __attribute__((ext_vector_type(8))) short bf16x8;
typedef __attribute__((ext_vector_type(4))) float f32x4;

static __device__ inline f32x4 mfma16(bf16x8 a, bf16x8 b, f32x4 c) {
    return __builtin_amdgcn_mfma_f32_16x16x32_bf16(a, b, c, 0, 0, 0);
}

static __device__ inline unsigned short f2bf(float f) {
    unsigned u = __builtin_bit_cast(unsigned, f);
    u += 0x7FFF + ((u >> 16) & 1);          /* RNE */
    return (unsigned short)(u >> 16);
}

/* A/B fragment (16x16x32): lane&15 = row(A)/col(B), 8 contiguous k at (lane>>4)*8.
   Build from fp32 global row-major (row stride 64), scaled, bf16-rounded. */
static __device__ inline bf16x8 gfrag(const float* p, float scale) {
    float4 a = *(const float4*)p;
    float4 b = *(const float4*)(p + 4);
    union { bf16x8 v; unsigned short s[8]; } u;
    u.s[0] = f2bf(a.x * scale); u.s[1] = f2bf(a.y * scale);
    u.s[2] = f2bf(a.z * scale); u.s[3] = f2bf(a.w * scale);
    u.s[4] = f2bf(b.x * scale); u.s[5] = f2bf(b.y * scale);
    u.s[6] = f2bf(b.z * scale); u.s[7] = f2bf(b.w * scale);
    return u.v;
}

// ---------------------------------------------------------------------------
// kstat: per (bh,chunk): rowK (=0.5||x||^2) + block max of (proj_k - h).
// ---------------------------------------------------------------------------
__global__ __launch_bounds__(256) void kstat_kernel(
    const float* __restrict__ kin, const float* __restrict__ omega,
    float* __restrict__ rowK, float* __restrict__ partial) {
    __shared__ float h_lds[128];
    __shared__ float wred[4];
    const int t = threadIdx.x, w = t >> 6, lane = t & 63;
    const int c16 = lane & 15, qd = lane >> 4;
    const int bx = blockIdx.x;
    const size_t rowbase = (size_t)(bx >> 5) * Nq + (size_t)(bx & 31) * Lq;
    const float* kb = kin + rowbase * 64;

    for (int rep = 0; rep < 32; ++rep) {          /* h pass: wave-per-row */
        int e = rep * 256 + t;
        int l = e >> 6;                            /* = rep*4 + w, wave-uniform */
        float x = kb[e] * SCALE;
        float s = x * x;
        #pragma unroll
        for (int o = 1; o <= 32; o <<= 1) s += __shfl_xor(s, o);
        if (lane == 0) { h_lds[l] = 0.5f * s; rowK[rowbase + l] = 0.5f * s; }
    }
    __syncthreads();

    f32x4 acc[2][8];
    #pragma unroll
    for (int i = 0; i < 2; ++i)
        #pragma unroll
        for (int nt = 0; nt < 8; ++nt) acc[i][nt] = (f32x4){0.f, 0.f, 0.f, 0.f};
    #pragma unroll
    for (int kt = 0; kt < 2; ++kt) {
        bf16x8 a0 = gfrag(kb + (size_t)(16 * (2 * w)     + c16) * 64 + kt * 32 + qd * 8, SCALE);
        bf16x8 a1 = gfrag(kb + (size_t)(16 * (2 * w + 1) + c16) * 64 + kt * 32 + qd * 8, SCALE);
        #pragma unroll
        for (int nt = 0; nt < 8; ++nt) {
            bf16x8 b = gfrag(omega + (size_t)(16 * nt + c16) * 64 + kt * 32 + qd * 8, 1.0f);
            acc[0][nt] = mfma16(a0, b, acc[0][nt]);
            acc[1][nt] = mfma16(a1, b, acc[1][nt]);
        }
    }
    float lmax = -1e30f;
    #pragma unroll
    for (int i = 0; i < 2; ++i) {
        const int row0 = 16 * (2 * w + i) + 4 * qd;
        #pragma unroll
        for (int r = 0; r < 4; ++r) {
            float h = h_lds[row0 + r];
            #pragma unroll
            for (int nt = 0; nt < 8; ++nt) lmax = fmaxf(lmax, acc[i][nt][r] - h);
        }
    }
    #pragma unroll
    for (int o = 1; o <= 32; o <<= 1) lmax = fmaxf(lmax, __shfl_xor(lmax, o));
    if (lane == 0) wred[w] = lmax;
    __syncthreads();
    if (t == 0)
        partial[bx] = fmaxf(fmaxf(wred[0], wred[1]), fmaxf(wred[2], wred[3]));
}

// ---------------------------------------------------------------------------
__global__ void gmax_kernel(const float* __restrict__ partial, int n, float* __restrict__ gmax) {
    float m = -1e30f;
    for (int i = threadIdx.x; i < n; i += 256) m = fmaxf(m, partial[i]);
    #pragma unroll
    for (int o = 1; o <= 32; o <<= 1) m = fmaxf(m, __shfl_xor(m, o));
    __shared__ float w[4];
    if ((threadIdx.x & 63) == 0) w[threadIdx.x >> 6] = m;
    __syncthreads();
    if (threadIdx.x == 0) gmax[0] = fmaxf(fmaxf(w[0], w[1]), fmaxf(w[2], w[3]));
}

// ---------------------------------------------------------------------------
// chunkstate: S_c = PK^T V (MFMA), z_c via appended ones-column.
// ---------------------------------------------------------------------------
__global__ __launch_bounds__(256) void chunkstate_kernel(
    const float* __restrict__ kin, const float* __restrict__ vin,
    const float* __restrict__ omega, const float* __restrict__ rowK,
    const float* __restrict__ gmaxp, float* __restrict__ Sbuf) {
    __shared__ __align__(16) unsigned short PKt[128 * KSTR]; /* [m][l] */
    __shared__ __align__(16) unsigned short Vt[80 * KSTR];   /* [d|1][l] */
    const int t = threadIdx.x, w = t >> 6, lane = t & 63;
    const int c16 = lane & 15, qd = lane >> 4;
    const int bx = blockIdx.x;
    const size_t rowbase = (size_t)(bx >> 5) * Nq + (size_t)(bx & 31) * Lq;
    const float* kb = kin + rowbase * 64;
    const float* vb = vin + rowbase * 64;
    const float gmax = gmaxp[0];

    f32x4 acc[2][8];
    #pragma unroll
    for (int i = 0; i < 2; ++i)
        #pragma unroll
        for (int nt = 0; nt < 8; ++nt) acc[i][nt] = (f32x4){0.f, 0.f, 0.f, 0.f};
    #pragma unroll
    for (int kt = 0; kt < 2; ++kt) {
        bf16x8 a0 = gfrag(kb + (size_t)(16 * (2 * w)     + c16) * 64 + kt * 32 + qd * 8, SCALE);
        bf16x8 a1 = gfrag(kb + (size_t)(16 * (2 * w + 1) + c16) * 64 + kt * 32 + qd * 8, SCALE);
        #pragma unroll
        for (int nt = 0; nt < 8; ++nt) {
            bf16x8 b = gfrag(omega + (size_t)(16 * nt + c16) * 64 + kt * 32 + qd * 8, 1.0f);
            acc[0][nt] = mfma16(a0, b, acc[0][nt]);
            acc[1][nt] = mfma16(a1, b, acc[1][nt]);
        }
    }
    #pragma unroll
    for (int i = 0; i < 2; ++i) {
        const int row0 = 16 * (2 * w + i) + 4 * qd;
        #pragma unroll
        for (int r = 0; r < 4; ++r) {
            float h = rowK[rowbase + row0 + r];
            #pragma unroll
            for (int nt = 0; nt < 8; ++nt) {
                float pk = __expf(acc[i][nt][r] - h - gmax) * INVSQRT_M + EPS_PHI;
                PKt[(16 * nt + c16) * KSTR + row0 + r] = f2bf(pk);
            }
        }
    }
    #pragma unroll
    for (int rep = 0; rep < 32; ++rep) {          /* Vt[d][l] = V[l][d] */
        int e = rep * 256 + t;
        Vt[(e & 63) * KSTR + (e >> 6)] = f2bf(vb[e]);
    }
    if (t < 128) Vt[64 * KSTR + t] = 0x3F80;      /* ones column -> z */
    __syncthreads();

    f32x4 acc2[2][5];
    #pragma unroll
    for (int i = 0; i < 2; ++i)
        #pragma unroll
        for (int nt = 0; nt < 5; ++nt) acc2[i][nt] = (f32x4){0.f, 0.f, 0.f, 0.f};
    #pragma unroll
    for (int kt = 0; kt < 4; ++kt) {
        bf16x8 a0 = *(const bf16x8*)&PKt[(16 * (2 * w)     + c16) * KSTR + kt * 32 + qd * 8];
        bf16x8 a1 = *(const bf16x8*)&PKt[(16 * (2 * w + 1) + c16) * KSTR + kt * 32 + qd * 8];
        #pragma unroll
        for (int nt = 0; nt < 5; ++nt) {
            bf16x8 b = *(const bf16x8*)&Vt[(16 * nt + c16) * KSTR + kt * 32 + qd * 8];
            acc2[0][nt] = mfma16(a0, b, acc2[0][nt]);
            acc2[1][nt] = mfma16(a1, b, acc2[1][nt]);
        }
    }
    float* sb = Sbuf + (size_t)bx * STATE_STRIDE;
    #pragma unroll
    for (int i = 0; i < 2; ++i) {
        const int m0 = 16 * (2 * w + i) + 4 * qd;
        #pragma unroll
        for (int r = 0; r < 4; ++r) {
            #pragma unroll
            for (int nt = 0; nt < 4; ++nt)
                sb[(m0 + r) * 64 + 16 * nt + c16] = acc2[i][nt][r];
            if (c16 == 0) sb[8192 + m0 + r] = acc2[i][4][r];
        }
    }
}

// ---------------------------------------------------------------------------
// prefix: in-place exclusive prefix of chunk states per (b,h).
// ---------------------------------------------------------------------------
__global__ __launch_bounds__(256) void prefix_kernel(float* __restrict__ Sbuf) {
    const int bh = blockIdx.x, t = threadIdx.x;
    for (int e = t; e < STATE_STRIDE; e += 256) {
        float running = 0.f;
        for (int c = 0; c < Cq; ++c) {
            size_t idx = ((size_t)bh * Cq + c) * STATE_STRIDE + e;
            float tmp = Sbuf[idx];
            Sbuf[idx] = running;
            running += tmp;
        }
    }
}

// ---------------------------------------------------------------------------
// replay: per (bh,chunk): proj via MFMA, phi, A_s = tril(PQ PK^T),
// [num|den] = [A_s|PQ] . [V,1 ; S_in,z_in]. One barrier total.
// ---------------------------------------------------------------------------
__global__ __launch_bounds__(256) void replay_kernel(
    const float* __restrict__ q, const float* __restrict__ kin,
    const float* __restrict__ vin, const float* __restrict__ omega,
    const float* __restrict__ rowK, const float* __restrict__ gmaxp,
    const float* __restrict__ Sbuf, float* __restrict__ out) {
    __shared__ __align__(16) unsigned short P[128 * PSTR];   /* [A_s | PQ] */
    __shared__ __align__(16) unsigned short PK[128 * KSTR];  /* [l][m] */
    __shared__ __align__(16) unsigned short Wt[80 * WSTR];   /* [d|wz][l;128+m] */
    const int t = threadIdx.x, w = t >> 6, lane = t & 63;
    const int c16 = lane & 15, qd = lane >> 4;
    const int bx = blockIdx.x;
    const size_t rowbase = (size_t)(bx >> 5) * Nq + (size_t)(bx & 31) * Lq;
    const float* qb = q + rowbase * 64;
    const float* kb = kin + rowbase * 64;
    const float* vb = vin + rowbase * 64;
    const float gmax = gmaxp[0];

    f32x4 acc[2][8];
    /* ---- proj_q ---- */
    #pragma unroll
    for (int i = 0; i < 2; ++i)
        #pragma unroll
        for (int nt = 0; nt < 8; ++nt) acc[i][nt] = (f32x4){0.f, 0.f, 0.f, 0.f};
    #pragma unroll
    for (int kt = 0; kt < 2; ++kt) {
        bf16x8 a0 = gfrag(qb + (size_t)(16 * (2 * w)     + c16) * 64 + kt * 32 + qd * 8, SCALE);
        bf16x8 a1 = gfrag(qb + (size_t)(16 * (2 * w + 1) + c16) * 64 + kt * 32 + qd * 8, SCALE);
        #pragma unroll
        for (int nt = 0; nt < 8; ++nt) {
            bf16x8 b = gfrag(omega + (size_t)(16 * nt + c16) * 64 + kt * 32 + qd * 8, 1.0f);
            acc[0][nt] = mfma16(a0, b, acc[0][nt]);
            acc[1][nt] = mfma16(a1, b, acc[1][nt]);
        }
    }
    /* ---- phi_q: h cancels against per-row max; write PQ into P[:,128:] ---- */
    #pragma unroll
    for (int i = 0; i < 2; ++i) {
        const int row0 = 16 * (2 * w + i) + 4 * qd;
        #pragma unroll
        for (int r = 0; r < 4; ++r) {
            float mx = acc[i][0][r];
            #pragma unroll
            for (int nt = 1; nt < 8; ++nt) mx = fmaxf(mx, acc[i][nt][r]);
            mx = fmaxf(mx, __shfl_xor(mx, 1));
            mx = fmaxf(mx, __shfl_xor(mx, 2));
            mx = fmaxf(mx, __shfl_xor(mx, 4));
            mx = fmaxf(mx, __shfl_xor(mx, 8));
            #pragma unroll
            for (int nt = 0; nt < 8; ++nt) {
                float pq = __expf(acc[i][nt][r] - mx) * INVSQRT_M + EPS_PHI;
                P[(row0 + r) * PSTR + 128 + 16 * nt + c16] = f2bf(pq);
            }
        }
    }
    /* ---- proj_k + phi_k -> PK[l][m] ---- */
    #pragma unroll
    for (int i = 0; i < 2; ++i)
        #pragma unroll
        for (int nt = 0; nt < 8; ++nt) acc[i][nt] = (f32x4){0.f, 0.f, 0.f, 0.f};
    #pragma unroll
    for (int kt = 0; kt < 2; ++kt) {
        bf16x8 a0 = gfrag(kb + (size_t)(16 * (2 * w)     + c16) * 64 + kt * 32 + qd * 8, SCALE);
        bf16x8 a1 = gfrag(kb + (size_t)(16 * (2 * w + 1) + c16) * 64 + kt * 32 + qd * 8, SCALE);
        #pragma unroll
        for (int nt = 0; nt < 8; ++nt) {
            bf16x8 b = gfrag(omega + (size_t)(16 * nt + c16) * 64 + kt * 32 + qd * 8, 1.0f);
            acc[0][nt] = mfma16(a0, b, acc[0][nt]);
            acc[1][nt] = mfma16(a1, b, acc[1][nt]);
        }
    }
    #pragma unroll
    for (int i = 0; i < 2; ++i) {
        const int row0 = 16 * (2 * w + i) + 4 * qd;
        #pragma unroll
        for (int r = 0; r < 4; ++r) {
            float h = rowK[rowbase + row0 + r];
            #pragma unroll
            for (int nt = 0; nt < 8; ++nt) {
                float pk = __expf(acc[i][nt][r] - h - gmax) * INVSQRT_M + EPS_PHI;
                PK[(row0 + r) * KSTR + 16 * nt + c16] = f2bf(pk);
            }
        }
    }
    /* ---- Wt fill: [V;S_in] transposed + w_z column ---- */
    const float* sb = Sbuf + (size_t)bx * STATE_STRIDE;
    #pragma unroll
    for (int rep = 0; rep < 32; ++rep) {
        int e = rep * 256 + t;
        Wt[(e & 63) * WSTR + (e >> 6)] = f2bf(vb[e]);
    }
    #pragma unroll
    for (int rep = 0; rep < 32; ++rep) {
        int e = rep * 256 + t;
        Wt[(e & 63) * WSTR + 128 + (e >> 6)] = f2bf(sb[e]);
    }
    if (t < 128) Wt[64 * WSTR + t] = 0x3F80;                  /* ones over V rows */
    else         Wt[64 * WSTR + t] = f2bf(sb[8192 + (t - 128)]); /* z_in over S rows */
    __syncthreads();   /* the ONE barrier: PK + Wt cross-wave visibility */

    /* ---- GEMM1: A_s = PQ . PK^T (A rows are wave-private) ---- */
    #pragma unroll
    for (int i = 0; i < 2; ++i)
        #pragma unroll
        for (int nt = 0; nt < 8; ++nt) acc[i][nt] = (f32x4){0.f, 0.f, 0.f, 0.f};
    #pragma unroll
    for (int kt = 0; kt < 4; ++kt) {
        bf16x8 a0 = *(const bf16x8*)&P[(16 * (2 * w)     + c16) * PSTR + 128 + kt * 32 + qd * 8];
        bf16x8 a1 = *(const bf16x8*)&P[(16 * (2 * w + 1) + c16) * PSTR + 128 + kt * 32 + qd * 8];
        #pragma unroll
        for (int nt = 0; nt < 8; ++nt) {
            bf16x8 b = *(const bf16x8*)&PK[(16 * nt + c16) * KSTR + kt * 32 + qd * 8];
            acc[0][nt] = mfma16(a0, b, acc[0][nt]);
            acc[1][nt] = mfma16(a1, b, acc[1][nt]);
        }
    }
    /* ---- causal mask + write A_s into P[:,0:128] (own rows) ---- */
    #pragma unroll
    for (int i = 0; i < 2; ++i) {
        const int row0 = 16 * (2 * w + i) + 4 * qd;
        #pragma unroll
        for (int r = 0; r < 4; ++r) {
            #pragma unroll
            for (int nt = 0; nt < 8; ++nt) {
                int col = 16 * nt + c16;
                float vm = (col <= row0 + r) ? acc[i][nt][r] : 0.f;
                P[(row0 + r) * PSTR + col] = f2bf(vm);
            }
        }
    }
    /* ---- GEMM2: [num|den] = P . Wt^T (A own rows, B ready since barrier) ---- */
    f32x4 acc2[2][5];
    #pragma unroll
    for (int i = 0; i < 2; ++i)
        #pragma unroll
        for (int nt = 0; nt < 5; ++nt) acc2[i][nt] = (f32x4){0.f, 0.f, 0.f, 0.f};
    #pragma unroll
    for (int kt = 0; kt < 8; ++kt) {
        bf16x8 a0 = *(const bf16x8*)&P[(16 * (2 * w)     + c16) * PSTR + kt * 32 + qd * 8];
        bf16x8 a1 = *(const bf16x8*)&P[(16 * (2 * w + 1) + c16) * PSTR + kt * 32 + qd * 8];
        #pragma unroll
        for (int nt = 0; nt < 5; ++nt) {
            bf16x8 b = *(const bf16x8*)&Wt[(16 * nt + c16) * WSTR + kt * 32 + qd * 8];
            acc2[0][nt] = mfma16(a0, b, acc2[0][nt]);
            acc2[1][nt] = mfma16(a1, b, acc2[1][nt]);
        }
    }
    /* ---- epilogue: den broadcast from col-64 holder lane (c16==0) ---- */
    #pragma unroll
    for (int i = 0; i < 2; ++i) {
        const int row0 = 16 * (2 * w + i) + 4 * qd;
        #pragma unroll
        for (int r = 0; r < 4; ++r) {
            float den = __shfl(acc2[i][4][r], lane & 48) + EPS_DEN;
            float rd = 1.0f / den;
            #pragma unroll
            for (int nt = 0; nt < 4; ++nt)
                out[(rowbase + row0 + r) * 64 + 16 * nt + c16] = acc2[i][nt][r] * rd;
        }
    }
}

// ---------------------------------------------------------------------------
extern "C" void kernel_launch(void* const* d_in, const int* in_sizes, int n_in,
                              void* d_out, int out_size, void* d_ws, size_t ws_size,
                              hipStream_t stream) {
    const float* q     = (const float*)d_in[0];
    const float* k     = (const float*)d_in[1];
    const float* v     = (const float*)d_in[2];
    const float* omega = (const float*)d_in[3];
    float* out = (float*)d_out;
    float* ws  = (float*)d_ws;

    const int totalRows = Bq * Hq * Nq;          /* 262144 */
    const int nChunks   = Bq * Hq * Cq;          /* 2048 */
    float* rowK    = ws;                         /* 262144 */
    float* partial = rowK + totalRows;           /* 2048 */
    float* gmax    = partial + nChunks;          /* 1 (+pad) */
    float* Sbuf    = gmax + 16;                  /* 2048 * 8320 = 68.2 MB (fits: R2 ran C=32) */

    kstat_kernel<<<nChunks, 256, 0, stream>>>(k, omega, rowK, partial);
    gmax_kernel<<<1, 256, 0, stream>>>(partial, nChunks, gmax);
    chunkstate_kernel<<<nChunks, 256, 0, stream>>>(k, v, omega, rowK, gmax, Sbuf);
    prefix_kernel<<<64, 256, 0, stream>>>(Sbuf);
    replay_kernel<<<nChunks, 256, 0, stream>>>(q, k, v, omega, rowK, gmax, Sbuf, out);
}